// Round 3
// baseline (558.949 us; speedup 1.0000x reference)
//
#include <hip/hip_runtime.h>
#include <hip/hip_bf16.h>
#include <math.h>

#define GENES 1000

typedef __attribute__((ext_vector_type(8))) short short8;
typedef __attribute__((ext_vector_type(8))) _Float16 half8;
typedef __attribute__((ext_vector_type(4))) float f32x4;
typedef __attribute__((ext_vector_type(4))) unsigned int uint4v;

// ---------------- CSR build ----------------

__global__ void k_deg(const int* __restrict__ ei, int* __restrict__ deg, int E) {
  int e = blockIdx.x * blockDim.x + threadIdx.x;
  if (e < E) atomicAdd(&deg[ei[E + e]], 1);
}

__global__ void k_scan(const int* __restrict__ deg, int* __restrict__ ptr, int n) {
  __shared__ int wsum[16];
  __shared__ int carry_s;
  int t = threadIdx.x;
  int lane = t & 63, w = t >> 6;
  if (t == 0) { carry_s = 0; ptr[0] = 0; }
  __syncthreads();
  for (int base = 0; base < n; base += 1024) {
    int i = base + t;
    int x = (i < n) ? deg[i] : 0;
    #pragma unroll
    for (int d = 1; d < 64; d <<= 1) {
      int y = __shfl_up(x, d);
      if (lane >= d) x += y;
    }
    if (lane == 63) wsum[w] = x;
    __syncthreads();
    if (t == 0) {
      int s = 0;
      #pragma unroll
      for (int k = 0; k < 16; ++k) { s += wsum[k]; wsum[k] = s; }
    }
    __syncthreads();
    int woff = (w == 0) ? 0 : wsum[w - 1];
    int incl = carry_s + woff + x;
    if (i < n) ptr[i + 1] = incl;
    __syncthreads();
    if (t == 1023) carry_s = incl;
    __syncthreads();
  }
}

__global__ void k_scatter(const int* __restrict__ ei, const int* __restrict__ ptr,
                          int* __restrict__ cur, int* __restrict__ srcs, int E) {
  int e = blockIdx.x * blockDim.x + threadIdx.x;
  if (e >= E) return;
  int d = ei[E + e];
  int pos = ptr[d] + atomicAdd(&cur[d], 1);
  srcs[pos] = ei[e];
}

// ---------------- W convert/transpose: W[K x N] fp32 -> Wt[128][1024] fp16 ----------------

__global__ void k_wconv(const float* __restrict__ W, unsigned short* __restrict__ Wt,
                        int K, int N) {
  int t = blockIdx.x * blockDim.x + threadIdx.x;  // over 128*1024
  if (t >= 128 * 1024) return;
  int col = t >> 10, k = t & 1023;
  float v = (k < K && col < N) ? W[(long)k * N + col] : 0.f;
  _Float16 h = (_Float16)v;   // RNE
  Wt[t] = __builtin_bit_cast(unsigned short, h);
}

// ---------------- MFMA fp16 GEMM: A[MxK] fp32 @ Wt -> out[Mx128] fp32 ----------------
// BM=64, BN=128, BK=32; 4 waves, wave w owns rows 0..63 x cols [w*32, w*32+32).
// LDS k-quarter-major: As[4][64][8], Bs[4][128][8] -> conflict-free writes & frag reads.

__global__ __launch_bounds__(256) void k_mgemm(
    const float* __restrict__ A, const unsigned short* __restrict__ Wt,
    float* __restrict__ out, int M, int K) {
  __shared__ unsigned short As[4 * 64 * 8];
  __shared__ unsigned short Bs[4 * 128 * 8];
  int t = threadIdx.x;
  int lane = t & 63, w = t >> 6;
  long row0 = (long)blockIdx.x * 64;

  f32x4 acc[4][2];
  #pragma unroll
  for (int m = 0; m < 4; ++m)
    #pragma unroll
    for (int n = 0; n < 2; ++n)
      acc[m][n] = (f32x4){0.f, 0.f, 0.f, 0.f};

  int ar = t & 63, aq = t >> 6;    // A staging: row = lane, k-quarter = wave
  int bc = t & 127, bh = t >> 7;   // B staging: col, k-half
  const float* ap = A + (row0 + ar) * (long)K + aq * 8;
  bool aok = (row0 + ar) < M;
  const unsigned short* bp = Wt + ((long)bc << 10) + bh * 16;

  int ksteps = (K + 31) >> 5;
  float av[8];
  short8 bv0, bv1;

  auto loadA = [&](int s) {
    int kb = s * 32 + aq * 8;
    if (aok && kb + 8 <= K) {
      float4 v0 = *(const float4*)(ap + s * 32);
      float4 v1 = *(const float4*)(ap + s * 32 + 4);
      av[0] = v0.x; av[1] = v0.y; av[2] = v0.z; av[3] = v0.w;
      av[4] = v1.x; av[5] = v1.y; av[6] = v1.z; av[7] = v1.w;
    } else {
      #pragma unroll
      for (int i = 0; i < 8; ++i)
        av[i] = (aok && kb + i < K) ? ap[s * 32 + i] : 0.f;
    }
  };
  auto loadB = [&](int s) {
    bv0 = *(const short8*)(bp + s * 32);
    bv1 = *(const short8*)(bp + s * 32 + 8);
  };

  loadA(0); loadB(0);
  for (int s = 0; s < ksteps; ++s) {
    // ---- convert + stage (tile s) ----
    uint4v ahu;
    #pragma unroll
    for (int i = 0; i < 4; ++i)
      ahu[i] = __builtin_bit_cast(unsigned int,
               __builtin_amdgcn_cvt_pkrtz(av[2 * i], av[2 * i + 1]));
    *(uint4v*)&As[(aq * 64 + ar) * 8] = ahu;
    *(short8*)&Bs[((2 * bh) * 128 + bc) * 8] = bv0;
    *(short8*)&Bs[((2 * bh + 1) * 128 + bc) * 8] = bv1;
    __syncthreads();
    // ---- prefetch tile s+1 (latency hides under MFMA phase) ----
    if (s + 1 < ksteps) { loadA(s + 1); loadB(s + 1); }
    // ---- fragments + MFMA ----
    int q = lane >> 4, r15 = lane & 15;
    half8 af[4];
    #pragma unroll
    for (int m = 0; m < 4; ++m)
      af[m] = *(const half8*)&As[(q * 64 + m * 16 + r15) * 8];
    #pragma unroll
    for (int n = 0; n < 2; ++n) {
      half8 bf = *(const half8*)&Bs[(q * 128 + w * 32 + n * 16 + r15) * 8];
      #pragma unroll
      for (int m = 0; m < 4; ++m)
        acc[m][n] = __builtin_amdgcn_mfma_f32_16x16x32_f16(af[m], bf, acc[m][n], 0, 0, 0);
    }
    __syncthreads();
  }
  // ---- epilogue: C/D layout col=lane&15, row=(lane>>4)*4+i ----
  int cc = lane & 15, cq = lane >> 4;
  #pragma unroll
  for (int m = 0; m < 4; ++m) {
    #pragma unroll
    for (int i = 0; i < 4; ++i) {
      long row = row0 + m * 16 + cq * 4 + i;
      if (row < M) {
        #pragma unroll
        for (int n = 0; n < 2; ++n)
          out[row * 128 + w * 32 + n * 16 + cc] = acc[m][n][i];
      }
    }
  }
}

// ---------------- attention coefficients ----------------

__global__ void k_al(const float* __restrict__ h, const float* __restrict__ a_s,
                     const float* __restrict__ a_d, float* __restrict__ als,
                     float* __restrict__ ald, int n, int H, int C, int lda) {
  int t = blockIdx.x * blockDim.x + threadIdx.x;
  if (t >= n * H) return;
  int hd = t % H, node = t / H;
  const float* hp = h + (long)node * lda + hd * C;
  float s1 = 0.f, s2 = 0.f;
  for (int c = 0; c < C; ++c) {
    float v = hp[c];
    s1 += v * a_s[hd * C + c];
    s2 += v * a_d[hd * C + c];
  }
  als[t] = s1; ald[t] = s2;
}

// ---------------- per-dst aggregation, H=8, C=16 (128 ch) ----------------

__global__ void k_agg128(const float* __restrict__ h, const float* __restrict__ als,
                         const float* __restrict__ ald, const int* __restrict__ ptr,
                         const int* __restrict__ srcs, const float* __restrict__ bias,
                         float* __restrict__ out, int n, int do_elu) {
  int wid = (int)(((long)blockIdx.x * blockDim.x + threadIdx.x) >> 6);
  if (wid >= n) return;
  int lane = threadIdx.x & 63;
  int p0 = ptr[wid], deg = ptr[wid + 1] - p0;
  int hA = lane & 7;
  float aldA = ald[wid * 8 + hA];
  float mx = -1e30f;
  for (int j = (lane >> 3); j < deg; j += 8) {
    float l = als[srcs[p0 + j] * 8 + hA] + aldA;
    l = l > 0.f ? l : 0.2f * l;
    mx = fmaxf(mx, l);
  }
  #pragma unroll
  for (int d = 8; d < 64; d <<= 1) mx = fmaxf(mx, __shfl_xor(mx, d));
  int hB = lane >> 3;
  float m = __shfl(mx, hB);
  float aldB = ald[wid * 8 + hB];
  int c0 = 2 * lane;
  float acc0 = 0.f, acc1 = 0.f, dsum = 0.f;
  for (int j = 0; j < deg; ++j) {
    int s = srcs[p0 + j];
    float l = als[s * 8 + hB] + aldB;
    l = l > 0.f ? l : 0.2f * l;
    float e = __expf(l - m);
    dsum += e;
    const float2 hv = *(const float2*)(h + (long)s * 128 + c0);
    acc0 += e * hv.x;
    acc1 += e * hv.y;
  }
  float inv = 1.f / (dsum + 1e-16f);
  float o0 = acc0 * inv + bias[c0];
  float o1 = acc1 * inv + bias[c0 + 1];
  if (do_elu) {
    o0 = o0 > 0.f ? o0 : (__expf(o0) - 1.f);
    o1 = o1 > 0.f ? o1 : (__expf(o1) - 1.f);
  }
  *(float2*)(out + (long)wid * 128 + c0) = make_float2(o0, o1);
}

// ---------------- per-dst aggregation, H=1, C=16 ----------------

__global__ void k_agg16(const float* __restrict__ h, const float* __restrict__ als,
                        const float* __restrict__ ald, const int* __restrict__ ptr,
                        const int* __restrict__ srcs, const float* __restrict__ bias,
                        float* __restrict__ out, int n, int lda) {
  int wid = (int)(((long)blockIdx.x * blockDim.x + threadIdx.x) >> 6);
  if (wid >= n) return;
  int lane = threadIdx.x & 63;
  int p0 = ptr[wid], deg = ptr[wid + 1] - p0;
  float aldv = ald[wid];
  float mx = -1e30f;
  for (int j = lane; j < deg; j += 64) {
    float l = als[srcs[p0 + j]] + aldv;
    l = l > 0.f ? l : 0.2f * l;
    mx = fmaxf(mx, l);
  }
  #pragma unroll
  for (int d = 1; d < 64; d <<= 1) mx = fmaxf(mx, __shfl_xor(mx, d));
  int g = lane >> 4, c = lane & 15;
  float acc = 0.f, dsum = 0.f;
  for (int j = g; j < deg; j += 4) {
    int s = srcs[p0 + j];
    float l = als[s] + aldv;
    l = l > 0.f ? l : 0.2f * l;
    float e = __expf(l - mx);
    dsum += e;
    acc += e * h[(long)s * lda + c];
  }
  #pragma unroll
  for (int d = 16; d < 64; d <<= 1) {
    acc += __shfl_xor(acc, d);
    dsum += __shfl_xor(dsum, d);
  }
  if (lane < 16)
    out[(long)wid * 16 + lane] = acc / (dsum + 1e-16f) + bias[lane];
}

// ---------------- launch ----------------

extern "C" void kernel_launch(void* const* d_in, const int* in_sizes, int n_in,
                              void* d_out, int out_size, void* d_ws, size_t ws_size,
                              hipStream_t stream) {
  const float* x  = (const float*)d_in[0];
  const int*   ei = (const int*)d_in[1];
  const float* W0 = (const float*)d_in[2];
  const float* as0= (const float*)d_in[3];
  const float* ad0= (const float*)d_in[4];
  const float* b0 = (const float*)d_in[5];
  const float* W1 = (const float*)d_in[6];
  const float* as1= (const float*)d_in[7];
  const float* ad1= (const float*)d_in[8];
  const float* b1 = (const float*)d_in[9];
  const float* W2 = (const float*)d_in[10];
  const float* as2= (const float*)d_in[11];
  const float* ad2= (const float*)d_in[12];
  const float* b2 = (const float*)d_in[13];
  float* out = (float*)d_out;

  int E = in_sizes[1] / 2;
  int n = in_sizes[0] / GENES;

  char* ws = (char*)d_ws;
  size_t off = 0;
  auto alloc = [&](size_t bytes) {
    void* p = ws + off;
    off = (off + bytes + 255) & ~(size_t)255;
    return p;
  };
  int* ptr   = (int*)alloc((size_t)(n + 1) * sizeof(int));
  int* cur   = (int*)alloc((size_t)n * sizeof(int));
  int* srcs  = (int*)alloc((size_t)E * sizeof(int));
  float* A   = (float*)alloc((size_t)n * 128 * sizeof(float));
  float* B   = (float*)alloc((size_t)n * 128 * sizeof(float));
  float* als = (float*)alloc((size_t)n * 8 * sizeof(float));
  float* ald = (float*)alloc((size_t)n * 8 * sizeof(float));
  unsigned short* Wt = (unsigned short*)alloc((size_t)128 * 1024 * sizeof(unsigned short));

  int eb = (E + 255) / 256;
  hipMemsetAsync(cur, 0, (size_t)n * sizeof(int), stream);
  k_deg<<<eb, 256, 0, stream>>>(ei, cur, E);
  k_scan<<<1, 1024, 0, stream>>>(cur, ptr, n);
  hipMemsetAsync(cur, 0, (size_t)n * sizeof(int), stream);
  k_scatter<<<eb, 256, 0, stream>>>(ei, ptr, cur, srcs, E);

  int mgb  = (n + 63) / 64;
  int aggb = (int)(((long)n * 64 + 255) / 256);
  int alb  = (n * 8 + 255) / 256;
  int alb1 = (n + 255) / 256;
  int wcb  = (128 * 1024) / 256;

  // layer 0: x @ W0 -> A, attention, aggregate -> B (ELU)
  k_wconv<<<wcb, 256, 0, stream>>>(W0, Wt, GENES, 128);
  k_mgemm<<<mgb, 256, 0, stream>>>(x, Wt, A, n, GENES);
  k_al<<<alb, 256, 0, stream>>>(A, as0, ad0, als, ald, n, 8, 16, 128);
  k_agg128<<<aggb, 256, 0, stream>>>(A, als, ald, ptr, srcs, b0, B, n, 1);

  // layer 1: B @ W1 -> A, aggregate -> B (ELU)
  k_wconv<<<wcb, 256, 0, stream>>>(W1, Wt, 128, 128);
  k_mgemm<<<mgb, 256, 0, stream>>>(B, Wt, A, n, 128);
  k_al<<<alb, 256, 0, stream>>>(A, as1, ad1, als, ald, n, 8, 16, 128);
  k_agg128<<<aggb, 256, 0, stream>>>(A, als, ald, ptr, srcs, b1, B, n, 1);

  // layer 2: B @ W2(padded to 128 cols) -> A (ld 128), aggregate -> out (no ELU)
  k_wconv<<<wcb, 256, 0, stream>>>(W2, Wt, 128, 16);
  k_mgemm<<<mgb, 256, 0, stream>>>(B, Wt, A, n, 128);
  k_al<<<alb1, 256, 0, stream>>>(A, as2, ad2, als, ald, n, 1, 16, 128);
  k_agg16<<<aggb, 256, 0, stream>>>(A, als, ald, ptr, srcs, b2, out, n, 128);
}

// Round 4
// 441.627 us; speedup vs baseline: 1.2657x; 1.2657x over previous
//
#include <hip/hip_runtime.h>
#include <hip/hip_bf16.h>
#include <math.h>

#define GENES 1000
#define KCH 256

typedef __attribute__((ext_vector_type(8))) _Float16 half8;
typedef __attribute__((ext_vector_type(4))) float f32x4;
typedef __attribute__((ext_vector_type(4))) unsigned int uint4v;

// ---------------- CSR build ----------------

__global__ void k_deg(const int* __restrict__ ei, int* __restrict__ deg, int E) {
  int e = blockIdx.x * blockDim.x + threadIdx.x;
  if (e < E) atomicAdd(&deg[ei[E + e]], 1);
}

// parallel scan: per-block inclusive scan + block sums
__global__ void k_scan1(const int* __restrict__ deg, int* __restrict__ ptr,
                        int* __restrict__ bsum, int n) {
  __shared__ int ws[4];
  int t = threadIdx.x, b = blockIdx.x;
  int i = b * 256 + t;
  int lane = t & 63, w = t >> 6;
  int x = (i < n) ? deg[i] : 0;
  #pragma unroll
  for (int d = 1; d < 64; d <<= 1) {
    int y = __shfl_up(x, d);
    if (lane >= d) x += y;
  }
  if (lane == 63) ws[w] = x;
  __syncthreads();
  if (t == 0) {
    int s = 0;
    #pragma unroll
    for (int k = 0; k < 4; ++k) { s += ws[k]; ws[k] = s; }
  }
  __syncthreads();
  int incl = x + (w ? ws[w - 1] : 0);
  if (i < n) ptr[i + 1] = incl;
  if (t == 255) bsum[b] = incl;
  if (i == 0) ptr[0] = 0;
}

// exclusive scan of block sums (nb <= 256), in place
__global__ void k_scan2(int* __restrict__ bsum, int nb) {
  __shared__ int ws[4];
  int t = threadIdx.x;
  int lane = t & 63, w = t >> 6;
  int v = (t < nb) ? bsum[t] : 0;
  int x = v;
  #pragma unroll
  for (int d = 1; d < 64; d <<= 1) {
    int y = __shfl_up(x, d);
    if (lane >= d) x += y;
  }
  if (lane == 63) ws[w] = x;
  __syncthreads();
  if (t == 0) {
    int s = 0;
    #pragma unroll
    for (int k = 0; k < 4; ++k) { s += ws[k]; ws[k] = s; }
  }
  __syncthreads();
  int incl = x + (w ? ws[w - 1] : 0);
  if (t < nb) bsum[t] = incl - v;
}

__global__ void k_scan3(int* __restrict__ ptr, const int* __restrict__ bsum, int n) {
  int i = blockIdx.x * 256 + threadIdx.x;
  if (i < n) ptr[i + 1] += bsum[blockIdx.x];
}

__global__ void k_scatter(const int* __restrict__ ei, const int* __restrict__ ptr,
                          int* __restrict__ cur, int* __restrict__ srcs, int E) {
  int e = blockIdx.x * blockDim.x + threadIdx.x;
  if (e >= E) return;
  int d = ei[E + e];
  int pos = ptr[d] + atomicAdd(&cur[d], 1);
  srcs[pos] = ei[e];
}

// ---------------- W pre-pack: fp32 [K][N] -> fp16 chunk-major swizzled ----------------
// chunk c (256 k), within chunk: byte = (ks*8192 + col*64 + kk*2) ^ ((col&7)<<4)

__global__ void k_wconv2(const float* __restrict__ W, unsigned short* __restrict__ Bpk,
                         int K, int N, int nch) {
  int t = blockIdx.x * blockDim.x + threadIdx.x;
  if (t >= nch * 32768) return;
  int c = t >> 15, r = t & 32767;
  int ks = r >> 12;
  int col = (r >> 5) & 127;
  int kk = r & 31;
  int k = c * 256 + ks * 32 + kk;
  float v = (k < K && col < N) ? W[(long)k * N + col] : 0.f;
  _Float16 h = (_Float16)v;
  unsigned byte = ((unsigned)r * 2) ^ (((unsigned)(col & 7)) << 4);
  *(unsigned short*)((char*)Bpk + (size_t)c * 65536 + byte) =
      __builtin_bit_cast(unsigned short, h);
}

// ---------------- MFMA fp16 GEMM, barrier-free inner loop ----------------
// 512 threads = 8 waves; wave owns 16 rows x 128 cols. B chunk (<=64KB) in LDS.
// Fused epilogue: out write + attention coefficients als/ald (a_src/a_dst dots).

template<int HH, int NW, int KS>
__global__ __launch_bounds__(512) void k_mgemm2(
    const float* __restrict__ A, const unsigned short* __restrict__ Bpk,
    float* __restrict__ out, float* __restrict__ als, float* __restrict__ ald,
    const float* __restrict__ avs, const float* __restrict__ avd,
    int M, int K, int nch, int ldc) {
  __shared__ unsigned short Bs[32768];  // 64 KB
  int t = threadIdx.x;
  int lane = t & 63, w = t >> 6;
  int r15 = lane & 15, q = lane >> 4;
  long row = (long)blockIdx.x * 128 + w * 16 + r15;
  bool rok = row < M;
  const float* arow = A + row * (long)K;

  f32x4 acc[8];
  #pragma unroll
  for (int nt = 0; nt < 8; ++nt) acc[nt] = (f32x4){0.f, 0.f, 0.f, 0.f};

  for (int c = 0; c < nch; ++c) {
    if (c) __syncthreads();  // all waves done reading previous chunk
    {
      const char* src = (const char*)Bpk + (size_t)c * 65536;
      char* dst = (char*)&Bs[0];
      #pragma unroll
      for (int o = 0; o < KS * 8192; o += 8192)
        *(uint4v*)(dst + o + t * 16) = *(const uint4v*)(src + o + t * 16);
    }
    __syncthreads();
    // barrier-free compute over this chunk
    #pragma unroll
    for (int ks = 0; ks < KS; ++ks) {
      int k0 = c * KCH + ks * 32 + q * 8;
      float av[8];
      if (rok && k0 + 8 <= K) {
        float4 v0 = *(const float4*)(arow + k0);
        float4 v1 = *(const float4*)(arow + k0 + 4);
        av[0] = v0.x; av[1] = v0.y; av[2] = v0.z; av[3] = v0.w;
        av[4] = v1.x; av[5] = v1.y; av[6] = v1.z; av[7] = v1.w;
      } else {
        #pragma unroll
        for (int j = 0; j < 8; ++j)
          av[j] = (rok && k0 + j < K) ? arow[k0 + j] : 0.f;
      }
      uint4v au;
      #pragma unroll
      for (int i = 0; i < 4; ++i)
        au[i] = __builtin_bit_cast(unsigned int,
                __builtin_amdgcn_cvt_pkrtz(av[2 * i], av[2 * i + 1]));
      half8 af = __builtin_bit_cast(half8, au);
      #pragma unroll
      for (int nt = 0; nt < 8; ++nt) {
        int col = nt * 16 + r15;
        unsigned byte = (unsigned)(ks * 8192 + col * 64 + q * 16) ^
                        (((unsigned)(col & 7)) << 4);
        half8 bf = *(const half8*)((const char*)&Bs[0] + byte);
        acc[nt] = __builtin_amdgcn_mfma_f32_16x16x32_f16(af, bf, acc[nt], 0, 0, 0);
      }
    }
  }
  // ---- epilogue: C/D layout col=lane&15, row=(lane>>4)*4+i ----
  long rbase = (long)blockIdx.x * 128 + w * 16 + q * 4;
  #pragma unroll
  for (int i = 0; i < 4; ++i) {
    long r = rbase + i;
    if (r < M) {
      #pragma unroll
      for (int nt = 0; nt < NW; ++nt)
        out[r * ldc + nt * 16 + r15] = acc[nt][i];
    }
  }
  // fused attention coefficients: als/ald per (row, head)
  #pragma unroll
  for (int h = 0; h < HH; ++h) {
    float cs = avs[h * 16 + r15];
    float cd = avd[h * 16 + r15];
    #pragma unroll
    for (int i = 0; i < 4; ++i) {
      float s1 = acc[h][i] * cs;
      float s2 = acc[h][i] * cd;
      #pragma unroll
      for (int d = 1; d < 16; d <<= 1) {
        s1 += __shfl_xor(s1, d);
        s2 += __shfl_xor(s2, d);
      }
      if (r15 == 0) {
        long r = rbase + i;
        if (r < M) { als[r * HH + h] = s1; ald[r * HH + h] = s2; }
      }
    }
  }
}

// ---------------- per-dst aggregation, H=8, C=16 (128 ch) ----------------

__global__ void k_agg128(const float* __restrict__ h, const float* __restrict__ als,
                         const float* __restrict__ ald, const int* __restrict__ ptr,
                         const int* __restrict__ srcs, const float* __restrict__ bias,
                         float* __restrict__ out, int n, int do_elu) {
  int wid = (int)(((long)blockIdx.x * blockDim.x + threadIdx.x) >> 6);
  if (wid >= n) return;
  int lane = threadIdx.x & 63;
  int p0 = ptr[wid], deg = ptr[wid + 1] - p0;
  int hA = lane & 7;
  float aldA = ald[wid * 8 + hA];
  float mx = -1e30f;
  for (int j = (lane >> 3); j < deg; j += 8) {
    float l = als[srcs[p0 + j] * 8 + hA] + aldA;
    l = l > 0.f ? l : 0.2f * l;
    mx = fmaxf(mx, l);
  }
  #pragma unroll
  for (int d = 8; d < 64; d <<= 1) mx = fmaxf(mx, __shfl_xor(mx, d));
  int hB = lane >> 3;
  float m = __shfl(mx, hB);
  float aldB = ald[wid * 8 + hB];
  int c0 = 2 * lane;
  float acc0 = 0.f, acc1 = 0.f, dsum = 0.f;
  for (int j = 0; j < deg; ++j) {
    int s = srcs[p0 + j];
    float l = als[s * 8 + hB] + aldB;
    l = l > 0.f ? l : 0.2f * l;
    float e = __expf(l - m);
    dsum += e;
    const float2 hv = *(const float2*)(h + (long)s * 128 + c0);
    acc0 += e * hv.x;
    acc1 += e * hv.y;
  }
  float inv = 1.f / (dsum + 1e-16f);
  float o0 = acc0 * inv + bias[c0];
  float o1 = acc1 * inv + bias[c0 + 1];
  if (do_elu) {
    o0 = o0 > 0.f ? o0 : (__expf(o0) - 1.f);
    o1 = o1 > 0.f ? o1 : (__expf(o1) - 1.f);
  }
  *(float2*)(out + (long)wid * 128 + c0) = make_float2(o0, o1);
}

// ---------------- per-dst aggregation, H=1, C=16 ----------------

__global__ void k_agg16(const float* __restrict__ h, const float* __restrict__ als,
                        const float* __restrict__ ald, const int* __restrict__ ptr,
                        const int* __restrict__ srcs, const float* __restrict__ bias,
                        float* __restrict__ out, int n, int lda) {
  int wid = (int)(((long)blockIdx.x * blockDim.x + threadIdx.x) >> 6);
  if (wid >= n) return;
  int lane = threadIdx.x & 63;
  int p0 = ptr[wid], deg = ptr[wid + 1] - p0;
  float aldv = ald[wid];
  float mx = -1e30f;
  for (int j = lane; j < deg; j += 64) {
    float l = als[srcs[p0 + j]] + aldv;
    l = l > 0.f ? l : 0.2f * l;
    mx = fmaxf(mx, l);
  }
  #pragma unroll
  for (int d = 1; d < 64; d <<= 1) mx = fmaxf(mx, __shfl_xor(mx, d));
  int g = lane >> 4, c = lane & 15;
  float acc = 0.f, dsum = 0.f;
  for (int j = g; j < deg; j += 4) {
    int s = srcs[p0 + j];
    float l = als[s] + aldv;
    l = l > 0.f ? l : 0.2f * l;
    float e = __expf(l - mx);
    dsum += e;
    acc += e * h[(long)s * lda + c];
  }
  #pragma unroll
  for (int d = 16; d < 64; d <<= 1) {
    acc += __shfl_xor(acc, d);
    dsum += __shfl_xor(dsum, d);
  }
  if (lane < 16)
    out[(long)wid * 16 + lane] = acc / (dsum + 1e-16f) + bias[lane];
}

// ---------------- launch ----------------

extern "C" void kernel_launch(void* const* d_in, const int* in_sizes, int n_in,
                              void* d_out, int out_size, void* d_ws, size_t ws_size,
                              hipStream_t stream) {
  const float* x  = (const float*)d_in[0];
  const int*   ei = (const int*)d_in[1];
  const float* W0 = (const float*)d_in[2];
  const float* as0= (const float*)d_in[3];
  const float* ad0= (const float*)d_in[4];
  const float* b0 = (const float*)d_in[5];
  const float* W1 = (const float*)d_in[6];
  const float* as1= (const float*)d_in[7];
  const float* ad1= (const float*)d_in[8];
  const float* b1 = (const float*)d_in[9];
  const float* W2 = (const float*)d_in[10];
  const float* as2= (const float*)d_in[11];
  const float* ad2= (const float*)d_in[12];
  const float* b2 = (const float*)d_in[13];
  float* out = (float*)d_out;

  int E = in_sizes[1] / 2;
  int n = in_sizes[0] / GENES;

  char* ws = (char*)d_ws;
  size_t off = 0;
  auto alloc = [&](size_t bytes) {
    void* p = ws + off;
    off = (off + bytes + 255) & ~(size_t)255;
    return p;
  };
  int* ptr   = (int*)alloc((size_t)(n + 1) * sizeof(int));
  int* cur   = (int*)alloc((size_t)n * sizeof(int));
  int* bsum  = (int*)alloc(512 * sizeof(int));
  int* srcs  = (int*)alloc((size_t)E * sizeof(int));
  float* A   = (float*)alloc((size_t)n * 128 * sizeof(float));
  float* B   = (float*)alloc((size_t)n * 128 * sizeof(float));
  float* als = (float*)alloc((size_t)n * 8 * sizeof(float));
  float* ald = (float*)alloc((size_t)n * 8 * sizeof(float));
  unsigned short* Bpk = (unsigned short*)alloc((size_t)4 * 32768 * sizeof(unsigned short));

  int eb = (E + 255) / 256;
  int nb = (n + 255) / 256;
  hipMemsetAsync(cur, 0, (size_t)n * sizeof(int), stream);
  k_deg<<<eb, 256, 0, stream>>>(ei, cur, E);
  k_scan1<<<nb, 256, 0, stream>>>(cur, ptr, bsum, n);
  k_scan2<<<1, 256, 0, stream>>>(bsum, nb);
  k_scan3<<<nb, 256, 0, stream>>>(ptr, bsum, n);
  hipMemsetAsync(cur, 0, (size_t)n * sizeof(int), stream);
  k_scatter<<<eb, 256, 0, stream>>>(ei, ptr, cur, srcs, E);

  int mgb  = (n + 127) / 128;
  int aggb = (int)(((long)n * 64 + 255) / 256);

  // layer 0: x @ W0 -> A (+als/ald), aggregate -> B (ELU)
  k_wconv2<<<512, 256, 0, stream>>>(W0, Bpk, GENES, 128, 4);
  k_mgemm2<8, 8, 8><<<mgb, 512, 0, stream>>>(x, Bpk, A, als, ald, as0, ad0,
                                             n, GENES, 4, 128);
  k_agg128<<<aggb, 256, 0, stream>>>(A, als, ald, ptr, srcs, b0, B, n, 1);

  // layer 1: B @ W1 -> A (+als/ald), aggregate -> B (ELU)
  k_wconv2<<<128, 256, 0, stream>>>(W1, Bpk, 128, 128, 1);
  k_mgemm2<8, 8, 4><<<mgb, 512, 0, stream>>>(B, Bpk, A, als, ald, as1, ad1,
                                             n, 128, 1, 128);
  k_agg128<<<aggb, 256, 0, stream>>>(A, als, ald, ptr, srcs, b1, B, n, 1);

  // layer 2: B @ W2 (padded) -> A compact [n][16] (+als/ald H=1), aggregate -> out
  k_wconv2<<<128, 256, 0, stream>>>(W2, Bpk, 128, 16, 1);
  k_mgemm2<1, 1, 4><<<mgb, 512, 0, stream>>>(B, Bpk, A, als, ald, as2, ad2,
                                             n, 128, 1, 16);
  k_agg16<<<aggb, 256, 0, stream>>>(A, als, ald, ptr, srcs, b2, out, n, 16);
}

// Round 5
// 426.424 us; speedup vs baseline: 1.3108x; 1.0357x over previous
//
#include <hip/hip_runtime.h>
#include <hip/hip_bf16.h>
#include <math.h>

#define GENES 1000

typedef __attribute__((ext_vector_type(8))) _Float16 half8;
typedef __attribute__((ext_vector_type(4))) float f32x4;
typedef __attribute__((ext_vector_type(4))) unsigned int uint4v;

// ---------------- CSR build ----------------

__global__ void k_deg(const int* __restrict__ ei, int* __restrict__ deg, int E) {
  int e = blockIdx.x * blockDim.x + threadIdx.x;
  if (e < E) atomicAdd(&deg[ei[E + e]], 1);
}

__global__ void k_scan1(const int* __restrict__ deg, int* __restrict__ ptr,
                        int* __restrict__ bsum, int n) {
  __shared__ int ws[4];
  int t = threadIdx.x, b = blockIdx.x;
  int i = b * 256 + t;
  int lane = t & 63, w = t >> 6;
  int x = (i < n) ? deg[i] : 0;
  #pragma unroll
  for (int d = 1; d < 64; d <<= 1) {
    int y = __shfl_up(x, d);
    if (lane >= d) x += y;
  }
  if (lane == 63) ws[w] = x;
  __syncthreads();
  if (t == 0) {
    int s = 0;
    #pragma unroll
    for (int k = 0; k < 4; ++k) { s += ws[k]; ws[k] = s; }
  }
  __syncthreads();
  int incl = x + (w ? ws[w - 1] : 0);
  if (i < n) ptr[i + 1] = incl;
  if (t == 255) bsum[b] = incl;
  if (i == 0) ptr[0] = 0;
}

__global__ void k_scan2(int* __restrict__ bsum, int nb) {
  __shared__ int ws[4];
  int t = threadIdx.x;
  int lane = t & 63, w = t >> 6;
  int v = (t < nb) ? bsum[t] : 0;
  int x = v;
  #pragma unroll
  for (int d = 1; d < 64; d <<= 1) {
    int y = __shfl_up(x, d);
    if (lane >= d) x += y;
  }
  if (lane == 63) ws[w] = x;
  __syncthreads();
  if (t == 0) {
    int s = 0;
    #pragma unroll
    for (int k = 0; k < 4; ++k) { s += ws[k]; ws[k] = s; }
  }
  __syncthreads();
  int incl = x + (w ? ws[w - 1] : 0);
  if (t < nb) bsum[t] = incl - v;
}

__global__ void k_scan3(int* __restrict__ ptr, const int* __restrict__ bsum, int n) {
  int i = blockIdx.x * 256 + threadIdx.x;
  if (i < n) ptr[i + 1] += bsum[blockIdx.x];
}

__global__ void k_scatter(const int* __restrict__ ei, const int* __restrict__ ptr,
                          int* __restrict__ cur, int* __restrict__ srcs, int E) {
  int e = blockIdx.x * blockDim.x + threadIdx.x;
  if (e >= E) return;
  int d = ei[E + e];
  int pos = ptr[d] + atomicAdd(&cur[d], 1);
  srcs[pos] = ei[e];
}

// ---------------- W pre-pack: fp32 [K][N] -> fp16, 32KB chunks of 128 k ----------------
// chunk c: element r = ks*4096 + col*32 + kk; byte = 2r ^ ((col&7)<<4)

__global__ void k_wconv3(const float* __restrict__ W, unsigned short* __restrict__ Bpk,
                         int K, int N, int nch) {
  int t = blockIdx.x * blockDim.x + threadIdx.x;
  if (t >= nch * 16384) return;
  int c = t >> 14, r = t & 16383;
  int ks = r >> 12, col = (r >> 5) & 127, kk = r & 31;
  int k = c * 128 + ks * 32 + kk;
  float v = (k < K && col < N) ? W[(long)k * N + col] : 0.f;
  _Float16 h = (_Float16)v;
  unsigned byte = ((unsigned)r * 2) ^ (((unsigned)(col & 7)) << 4);
  *(unsigned short*)((char*)Bpk + (size_t)c * 32768 + byte) =
      __builtin_bit_cast(unsigned short, h);
}

// ---------------- MFMA fp16 GEMM, KCH=128, batch-issued A loads ----------------
// 256 threads = 4 waves; wave w owns rows w*16+r15, all 128 cols (NW tiles).
// Fused epilogue: out (fp16 or fp32) + attention coefficients als/ald.

template<int HH, int NW, bool AF16, bool OF16>
__global__ __launch_bounds__(256, 4) void k_mgemm3(
    const void* __restrict__ Ap, const unsigned short* __restrict__ Bpk,
    void* __restrict__ outp, float* __restrict__ als, float* __restrict__ ald,
    const float* __restrict__ avs, const float* __restrict__ avd,
    int M, int K, int ldc) {
  __shared__ unsigned short Bs[16384];  // 32 KB
  int t = threadIdx.x, lane = t & 63, w = t >> 6;
  int r15 = lane & 15, q = lane >> 4;
  long row = (long)blockIdx.x * 64 + w * 16 + r15;
  bool rok = row < M;
  const float* a32 = (const float*)Ap + row * (long)K;
  const unsigned short* a16 = (const unsigned short*)Ap + row * (long)K;

  f32x4 acc[NW];
  #pragma unroll
  for (int nt = 0; nt < NW; ++nt) acc[nt] = (f32x4){0.f, 0.f, 0.f, 0.f};

  int nch = (K + 127) >> 7;
  for (int c = 0; c < nch; ++c) {
    if (c) __syncthreads();  // previous chunk consumed
    // ---- A loads: all 4 k-steps issued before any use ----
    half8 af[4];
    if (AF16) {
      uint4v lb0, lb1, lb2, lb3;
      int k0 = c * 128 + q * 8;
      uint4v z = (uint4v){0u, 0u, 0u, 0u};
      lb0 = (rok && k0 + 8 <= K)   ? *(const uint4v*)(a16 + k0)      : z;
      lb1 = (rok && k0 + 40 <= K)  ? *(const uint4v*)(a16 + k0 + 32) : z;
      lb2 = (rok && k0 + 72 <= K)  ? *(const uint4v*)(a16 + k0 + 64) : z;
      lb3 = (rok && k0 + 104 <= K) ? *(const uint4v*)(a16 + k0 + 96) : z;
      af[0] = __builtin_bit_cast(half8, lb0);
      af[1] = __builtin_bit_cast(half8, lb1);
      af[2] = __builtin_bit_cast(half8, lb2);
      af[3] = __builtin_bit_cast(half8, lb3);
    } else {
      float4 l0[4], l1[4];
      #pragma unroll
      for (int ks = 0; ks < 4; ++ks) {
        int k0 = c * 128 + ks * 32 + q * 8;
        if (rok && k0 + 8 <= K) {
          l0[ks] = *(const float4*)(a32 + k0);
          l1[ks] = *(const float4*)(a32 + k0 + 4);
        } else {
          float tmp[8];
          #pragma unroll
          for (int j = 0; j < 8; ++j)
            tmp[j] = (rok && k0 + j < K) ? a32[k0 + j] : 0.f;
          l0[ks] = make_float4(tmp[0], tmp[1], tmp[2], tmp[3]);
          l1[ks] = make_float4(tmp[4], tmp[5], tmp[6], tmp[7]);
        }
      }
      #pragma unroll
      for (int ks = 0; ks < 4; ++ks) {
        uint4v au;
        au[0] = __builtin_bit_cast(unsigned int,
                __builtin_amdgcn_cvt_pkrtz(l0[ks].x, l0[ks].y));
        au[1] = __builtin_bit_cast(unsigned int,
                __builtin_amdgcn_cvt_pkrtz(l0[ks].z, l0[ks].w));
        au[2] = __builtin_bit_cast(unsigned int,
                __builtin_amdgcn_cvt_pkrtz(l1[ks].x, l1[ks].y));
        au[3] = __builtin_bit_cast(unsigned int,
                __builtin_amdgcn_cvt_pkrtz(l1[ks].z, l1[ks].w));
        af[ks] = __builtin_bit_cast(half8, au);
      }
    }
    // ---- stage B chunk (32 KB) into LDS ----
    {
      const uint4v* gs = (const uint4v*)((const char*)Bpk + (size_t)c * 32768);
      uint4v* ls = (uint4v*)&Bs[0];
      #pragma unroll
      for (int b = 0; b < 2; ++b) {
        uint4v tmp0 = gs[(b * 4 + 0) * 256 + t];
        uint4v tmp1 = gs[(b * 4 + 1) * 256 + t];
        uint4v tmp2 = gs[(b * 4 + 2) * 256 + t];
        uint4v tmp3 = gs[(b * 4 + 3) * 256 + t];
        ls[(b * 4 + 0) * 256 + t] = tmp0;
        ls[(b * 4 + 1) * 256 + t] = tmp1;
        ls[(b * 4 + 2) * 256 + t] = tmp2;
        ls[(b * 4 + 3) * 256 + t] = tmp3;
      }
    }
    __syncthreads();
    // ---- compute: 4 k-steps x NW col-tiles ----
    #pragma unroll
    for (int ks = 0; ks < 4; ++ks) {
      #pragma unroll
      for (int nt = 0; nt < NW; ++nt) {
        int col = nt * 16 + r15;
        unsigned byte = (unsigned)(ks * 8192 + col * 64 + q * 16) ^
                        (((unsigned)(col & 7)) << 4);
        half8 bf = *(const half8*)((const char*)&Bs[0] + byte);
        acc[nt] = __builtin_amdgcn_mfma_f32_16x16x32_f16(af[ks], bf, acc[nt], 0, 0, 0);
      }
    }
  }
  // ---- epilogue: C/D layout col=lane&15, row=(lane>>4)*4+i ----
  long rbase = (long)blockIdx.x * 64 + w * 16 + q * 4;
  if (OF16) {
    unsigned short* o16 = (unsigned short*)outp;
    #pragma unroll
    for (int i = 0; i < 4; ++i) {
      long r = rbase + i;
      if (r < M) {
        #pragma unroll
        for (int nt = 0; nt < NW; ++nt) {
          _Float16 hv = (_Float16)acc[nt][i];
          o16[r * ldc + nt * 16 + r15] = __builtin_bit_cast(unsigned short, hv);
        }
      }
    }
  } else {
    float* o32 = (float*)outp;
    #pragma unroll
    for (int i = 0; i < 4; ++i) {
      long r = rbase + i;
      if (r < M) {
        #pragma unroll
        for (int nt = 0; nt < NW; ++nt)
          o32[r * ldc + nt * 16 + r15] = acc[nt][i];
      }
    }
  }
  // fused attention coefficients
  #pragma unroll
  for (int h = 0; h < HH; ++h) {
    float cs = avs[h * 16 + r15];
    float cd = avd[h * 16 + r15];
    #pragma unroll
    for (int i = 0; i < 4; ++i) {
      float s1 = acc[h][i] * cs;
      float s2 = acc[h][i] * cd;
      #pragma unroll
      for (int d = 1; d < 16; d <<= 1) {
        s1 += __shfl_xor(s1, d);
        s2 += __shfl_xor(s2, d);
      }
      if (r15 == 0) {
        long r = rbase + i;
        if (r < M) { als[r * HH + h] = s1; ald[r * HH + h] = s2; }
      }
    }
  }
}

// ---------------- per-dst aggregation, H=8, C=16, fp16 h in / fp16 out, ELU ----------------

__global__ void k_agg128h(const unsigned short* __restrict__ h,
                          const float* __restrict__ als, const float* __restrict__ ald,
                          const int* __restrict__ ptr, const int* __restrict__ srcs,
                          const float* __restrict__ bias,
                          unsigned short* __restrict__ out, int n) {
  int wid = (int)(((long)blockIdx.x * blockDim.x + threadIdx.x) >> 6);
  if (wid >= n) return;
  int lane = threadIdx.x & 63;
  int p0 = ptr[wid], deg = ptr[wid + 1] - p0;
  int hA = lane & 7;
  float aldA = ald[wid * 8 + hA];
  float mx = -1e30f;
  for (int j = (lane >> 3); j < deg; j += 8) {
    float l = als[srcs[p0 + j] * 8 + hA] + aldA;
    l = l > 0.f ? l : 0.2f * l;
    mx = fmaxf(mx, l);
  }
  #pragma unroll
  for (int d = 8; d < 64; d <<= 1) mx = fmaxf(mx, __shfl_xor(mx, d));
  int hB = lane >> 3;
  float m = __shfl(mx, hB);
  float aldB = ald[wid * 8 + hB];
  int c0 = 2 * lane;
  float acc0 = 0.f, acc1 = 0.f, dsum = 0.f;
  for (int j = 0; j < deg; ++j) {
    int s = srcs[p0 + j];
    float l = als[s * 8 + hB] + aldB;
    l = l > 0.f ? l : 0.2f * l;
    float e = __expf(l - m);
    dsum += e;
    unsigned int hv = *(const unsigned int*)(h + (long)s * 128 + c0);
    float f0 = (float)__builtin_bit_cast(_Float16, (unsigned short)(hv & 0xffffu));
    float f1 = (float)__builtin_bit_cast(_Float16, (unsigned short)(hv >> 16));
    acc0 += e * f0;
    acc1 += e * f1;
  }
  float inv = 1.f / (dsum + 1e-16f);
  float o0 = acc0 * inv + bias[c0];
  float o1 = acc1 * inv + bias[c0 + 1];
  o0 = o0 > 0.f ? o0 : (__expf(o0) - 1.f);
  o1 = o1 > 0.f ? o1 : (__expf(o1) - 1.f);
  unsigned int po = __builtin_bit_cast(unsigned int, __builtin_amdgcn_cvt_pkrtz(o0, o1));
  *(unsigned int*)(out + (long)wid * 128 + c0) = po;
}

// ---------------- per-dst aggregation, H=1, C=16, fp32 ----------------

__global__ void k_agg16(const float* __restrict__ h, const float* __restrict__ als,
                        const float* __restrict__ ald, const int* __restrict__ ptr,
                        const int* __restrict__ srcs, const float* __restrict__ bias,
                        float* __restrict__ out, int n, int lda) {
  int wid = (int)(((long)blockIdx.x * blockDim.x + threadIdx.x) >> 6);
  if (wid >= n) return;
  int lane = threadIdx.x & 63;
  int p0 = ptr[wid], deg = ptr[wid + 1] - p0;
  float aldv = ald[wid];
  float mx = -1e30f;
  for (int j = lane; j < deg; j += 64) {
    float l = als[srcs[p0 + j]] + aldv;
    l = l > 0.f ? l : 0.2f * l;
    mx = fmaxf(mx, l);
  }
  #pragma unroll
  for (int d = 1; d < 64; d <<= 1) mx = fmaxf(mx, __shfl_xor(mx, d));
  int g = lane >> 4, c = lane & 15;
  float acc = 0.f, dsum = 0.f;
  for (int j = g; j < deg; j += 4) {
    int s = srcs[p0 + j];
    float l = als[s] + aldv;
    l = l > 0.f ? l : 0.2f * l;
    float e = __expf(l - mx);
    dsum += e;
    acc += e * h[(long)s * lda + c];
  }
  #pragma unroll
  for (int d = 16; d < 64; d <<= 1) {
    acc += __shfl_xor(acc, d);
    dsum += __shfl_xor(dsum, d);
  }
  if (lane < 16)
    out[(long)wid * 16 + lane] = acc / (dsum + 1e-16f) + bias[lane];
}

// ---------------- launch ----------------

extern "C" void kernel_launch(void* const* d_in, const int* in_sizes, int n_in,
                              void* d_out, int out_size, void* d_ws, size_t ws_size,
                              hipStream_t stream) {
  const float* x  = (const float*)d_in[0];
  const int*   ei = (const int*)d_in[1];
  const float* W0 = (const float*)d_in[2];
  const float* as0= (const float*)d_in[3];
  const float* ad0= (const float*)d_in[4];
  const float* b0 = (const float*)d_in[5];
  const float* W1 = (const float*)d_in[6];
  const float* as1= (const float*)d_in[7];
  const float* ad1= (const float*)d_in[8];
  const float* b1 = (const float*)d_in[9];
  const float* W2 = (const float*)d_in[10];
  const float* as2= (const float*)d_in[11];
  const float* ad2= (const float*)d_in[12];
  const float* b2 = (const float*)d_in[13];
  float* out = (float*)d_out;

  int E = in_sizes[1] / 2;
  int n = in_sizes[0] / GENES;

  char* ws = (char*)d_ws;
  size_t off = 0;
  auto alloc = [&](size_t bytes) {
    void* p = ws + off;
    off = (off + bytes + 255) & ~(size_t)255;
    return p;
  };
  int* ptr   = (int*)alloc((size_t)(n + 1) * sizeof(int));
  int* cur   = (int*)alloc((size_t)n * sizeof(int));
  int* bsum  = (int*)alloc(512 * sizeof(int));
  int* srcs  = (int*)alloc((size_t)E * sizeof(int));
  unsigned short* Ah = (unsigned short*)alloc((size_t)n * 128 * sizeof(unsigned short));
  unsigned short* Bh = (unsigned short*)alloc((size_t)n * 128 * sizeof(unsigned short));
  float* A2  = (float*)alloc((size_t)n * 16 * sizeof(float));
  float* als = (float*)alloc((size_t)n * 8 * sizeof(float));
  float* ald = (float*)alloc((size_t)n * 8 * sizeof(float));
  unsigned short* Bpk = (unsigned short*)alloc((size_t)8 * 16384 * sizeof(unsigned short));

  int eb = (E + 255) / 256;
  int nb = (n + 255) / 256;
  hipMemsetAsync(cur, 0, (size_t)n * sizeof(int), stream);
  k_deg<<<eb, 256, 0, stream>>>(ei, cur, E);
  k_scan1<<<nb, 256, 0, stream>>>(cur, ptr, bsum, n);
  k_scan2<<<1, 256, 0, stream>>>(bsum, nb);
  k_scan3<<<nb, 256, 0, stream>>>(ptr, bsum, n);
  hipMemsetAsync(cur, 0, (size_t)n * sizeof(int), stream);
  k_scatter<<<eb, 256, 0, stream>>>(ei, ptr, cur, srcs, E);

  int mgb  = (n + 63) / 64;
  int aggb = (int)(((long)n * 64 + 255) / 256);

  // layer 0: x @ W0 -> Ah fp16 (+als/ald), aggregate -> Bh fp16 (ELU)
  k_wconv3<<<512, 256, 0, stream>>>(W0, Bpk, GENES, 128, 8);
  k_mgemm3<8, 8, false, true><<<mgb, 256, 0, stream>>>(
      x, Bpk, Ah, als, ald, as0, ad0, n, GENES, 128);
  k_agg128h<<<aggb, 256, 0, stream>>>(Ah, als, ald, ptr, srcs, b0, Bh, n);

  // layer 1: Bh @ W1 -> Ah fp16 (+als/ald), aggregate -> Bh fp16 (ELU)
  k_wconv3<<<64, 256, 0, stream>>>(W1, Bpk, 128, 128, 1);
  k_mgemm3<8, 8, true, true><<<mgb, 256, 0, stream>>>(
      Bh, Bpk, Ah, als, ald, as1, ad1, n, 128, 128);
  k_agg128h<<<aggb, 256, 0, stream>>>(Ah, als, ald, ptr, srcs, b1, Bh, n);

  // layer 2: Bh @ W2 (padded) -> A2 fp32 [n][16] (+als/ald H=1), aggregate -> out
  k_wconv3<<<64, 256, 0, stream>>>(W2, Bpk, 128, 16, 1);
  k_mgemm3<1, 1, true, false><<<mgb, 256, 0, stream>>>(
      Bh, Bpk, A2, als, ald, as2, ad2, n, 128, 16);
  k_agg16<<<aggb, 256, 0, stream>>>(A2, als, ald, ptr, srcs, b2, out, n, 16);
}